// Round 9
// baseline (41.287 us; speedup 1.0000x reference)
//
#include <hip/hip_runtime.h>

typedef _Float16 f16;
typedef _Float16 f16x2 __attribute__((ext_vector_type(2)));
typedef __fp16 fp16x2 __attribute__((ext_vector_type(2)));
typedef _Float16 f16x8 __attribute__((ext_vector_type(8)));
typedef float f32x4 __attribute__((ext_vector_type(4)));
typedef unsigned int u32;

union U2 { u32 u; f16x2 h; fp16x2 h2; };
union AF { f16x8 v; u32 u[4]; };

// ---------------- pre kernel 1: W3eff (computed ONCE, coalesced, MLP'd) ----
__global__ __launch_bounds__(256) void pre_w3eff(
    const float* __restrict__ W3, const float* __restrict__ W_out,
    float* __restrict__ W3eff) {
    const int idx = blockIdx.x * 256 + threadIdx.x;  // 2048 = (h,m)
    float acc[8] = {0.f, 0.f, 0.f, 0.f, 0.f, 0.f, 0.f, 0.f};
#pragma unroll
    for (int ob = 0; ob < 8; ++ob)
#pragma unroll
        for (int oi = 0; oi < 8; ++oi) {
            int o = ob * 8 + oi;
            acc[oi] += W_out[128 + o] * W3[o * 2048 + idx];
        }
    float s = 0.f;
#pragma unroll
    for (int oi = 0; oi < 8; ++oi) s += acc[oi];
    W3eff[idx] = s;
}

// ---------------- pre kernel 2: Wfrag + rvec + cnst (unchanged format) -----
__global__ __launch_bounds__(256) void pre_rest(
    const float* __restrict__ W1, const float* __restrict__ b1,
    const float* __restrict__ W2, const float* __restrict__ b2,
    const float* __restrict__ b3, const float* __restrict__ W_out,
    const float* __restrict__ b_out, const float* __restrict__ W3eff_g,
    f16* __restrict__ Wfrag, float* __restrict__ rvec, float* __restrict__ cnst) {
    const int blk = blockIdx.x, t = threadIdx.x;
    if (blk < 64) {
        const int h = blk;
        __shared__ float w3e[2048];
        __shared__ float w2s[2048];
        __shared__ float wo2[64];
#pragma unroll
        for (int i = 0; i < 8; ++i) {
            int idx = t + 256 * i;
            w3e[idx] = W3eff_g[idx];
            w2s[idx] = W2[((idx >> 5) * 64 + h) * 32 + (idx & 31)];
        }
        if (t < 64) wo2[t] = W_out[64 + t];
        __syncthreads();
        for (int idx = t; idx < 576; idx += 256) {
            int c = idx >> 5, kk = idx & 31;
            int sg = c >> 1, par = c & 1, A = kk >> 1, z = kk & 1;
            int B = (A + sg) & 15;
            float val = 0.f;
            if (sg == 0 && par == 1 && z == 1) {
                val = 0.f;
            } else if (sg == 8 && A >= 8) {
                int m = par ? (kk - 16) : kk;
                float s = 0.f;
#pragma unroll 8
                for (int o = 0; o < 64; ++o) s += wo2[o] * w2s[o * 32 + m];
                val = s;
            } else {
                int a = 2 * A + (par ? (1 - z) : z);
                int bq = 2 * B + z;
                float s = 0.f;
                if (a == bq) {
#pragma unroll 8
                    for (int o = 0; o < 64; ++o)
                        s += w3e[o * 32 + a] * w2s[o * 32 + a];
                } else {
#pragma unroll 8
                    for (int o = 0; o < 64; ++o)
                        s += w3e[o * 32 + bq] * w2s[o * 32 + a] +
                             w3e[o * 32 + a] * w2s[o * 32 + bq];
                }
                val = s;
            }
            int g = (kk >> 2) & 3, bb = (kk & 3) + 4 * (kk >> 4);
            int t4 = 4 + (h >> 4), l = 16 * g + (h & 15);
            Wfrag[((c * 8 + t4) * 64 + l) * 8 + bb] = (f16)val;
        }
    } else if (blk < 128) {
        const int h = blk - 64;
        __shared__ float w1r[1024];
        for (int i = t; i < 1024; i += 256) w1r[i] = W1[h * 1024 + i];
        __syncthreads();
        for (int idx = t; idx < 576; idx += 256) {
            int c = idx >> 5, kk = idx & 31;
            int sg = c >> 1, par = c & 1, A = kk >> 1, z = kk & 1;
            int B = (A + sg) & 15;
            float val = 0.f;
            if ((sg == 0 && par == 1 && z == 1) || (sg == 8 && A >= 8)) {
                val = 0.f;
            } else {
                int a = 2 * A + (par ? (1 - z) : z);
                int bq = 2 * B + z;
                val = (a == bq) ? w1r[33 * a] : (w1r[32 * a + bq] + w1r[32 * bq + a]);
            }
            int g = (kk >> 2) & 3, bb = (kk & 3) + 4 * (kk >> 4);
            int t4 = h >> 4, l = 16 * g + (h & 15);
            Wfrag[((c * 8 + t4) * 64 + l) * 8 + bb] = (f16)val;
        }
    } else {
        if (t < 32) {
            float acc[8] = {0.f, 0.f, 0.f, 0.f, 0.f, 0.f, 0.f, 0.f};
#pragma unroll
            for (int hb = 0; hb < 8; ++hb)
#pragma unroll
                for (int hi = 0; hi < 8; ++hi) {
                    int h = hb * 8 + hi;
                    acc[hi] += b2[h] * W3eff_g[h * 32 + t];
                }
            float r = 0.f;
#pragma unroll
            for (int hi = 0; hi < 8; ++hi) r += acc[hi];
            rvec[t] = r;
        }
        if (t >= 64 && t < 128) {
            int o = t - 64;
            float v = b1[o] * W_out[o] + b2[o] * W_out[64 + o] +
                      b3[o] * W_out[128 + o];
#pragma unroll
            for (int off = 32; off; off >>= 1) v += __shfl_xor(v, off);
            if (o == 0) cnst[0] = b_out[0] + 64.f * v;
        }
    }
}

// ---------------- main kernel ----------------

__device__ __forceinline__ void gld16(const void* g, void* l) {
    __builtin_amdgcn_global_load_lds(
        (const __attribute__((address_space(1))) u32*)g,
        (__attribute__((address_space(3))) u32*)l, 16, 0, 0);
}

#define EPOS(row, col) ((row) * 64 + (((col) + 4 * (row)) & 63))

// Block: 4 batches (256 rows) x 128 cols, 4 waves (wr = batch-pair, wc = col
// half). FQ: per-batch 16 rows x 130 u32, FQ[bl][J][d] = {E[2J][d],E[2J+2][d]},
// E[m]=pack(v_m,v_{m+1}). B double-buffered in LDS via global_load_lds.
// Schedule (T3-minimum, 1 barrier/chunk): iter cc stages ch(cc+1) into the
// buffer whose reads completed BEFORE the previous barrier, computes buf[cc&1].
__global__ __launch_bounds__(256, 2) void cin_main(
    const float* __restrict__ x0, const f16* __restrict__ Wfrag,
    const float* __restrict__ b1, const float* __restrict__ W_out,
    const float* __restrict__ rvec, const float* __restrict__ cnst,
    float* __restrict__ out) {
    __shared__ __align__(16) u32 FQ[4 * 2080];   // 33280 B
    __shared__ __align__(16) char shB[16384];    // B dbuf; epilogue eps aliases
    __shared__ float b1s[64], w1s[64], rs[32], rvb[4], obuf[4][2];

    const int t = threadIdx.x;
    const int w = t >> 6, lane = t & 63;
    const int wr = w >> 1, wc = w & 1;
    const int g = (lane >> 4) & 3, l15 = lane & 15;
    const int blk = blockIdx.x;

    const char* WfB = reinterpret_cast<const char*>(Wfrag);

#define STAGE(buf, ch)                                              \
    do {                                                            \
        const char* gs_ = WfB + (ch) * 8192 + w * 2048 + lane * 16; \
        char* ls_ = shB + (buf) * 8192 + w * 2048;                  \
        gld16(gs_, ls_);                                            \
        gld16(gs_ + 1024, ls_ + 1024);                              \
    } while (0)

    STAGE(0, 0);

    {   // stage x0 (4 batches) -> FQ (16 rows per batch)
        const float* src = x0 + (size_t)blk * 8192;
        const int J = t >> 4, l = t & 15;  // J in [0,16)
        int r0 = 2 * J, r1 = 2 * J + 1, r2_ = (2 * J + 2) & 31, r3_ = (2 * J + 3) & 31;
#pragma unroll
        for (int bl = 0; bl < 4; ++bl) {
            const float* sb = src + bl * 2048;
#pragma unroll
            for (int k2 = 0; k2 < 4; ++k2) {
                int d = 16 * k2 + l;
                U2 u0, u1;
                u0.h2 = __builtin_amdgcn_cvt_pkrtz(sb[r0 * 64 + d], sb[r1 * 64 + d]);
                u1.h2 = __builtin_amdgcn_cvt_pkrtz(sb[r2_ * 64 + d], sb[r3_ * 64 + d]);
                uint2 ent; ent.x = u0.u; ent.y = u1.u;
                *reinterpret_cast<uint2*>(&FQ[bl * 2080 + J * 130 + 2 * d]) = ent;
            }
        }
    }
    if (t < 64) { b1s[t] = b1[t]; w1s[t] = W_out[t]; }
    if (t >= 64 && t < 96) rs[t - 64] = rvec[t - 64];
    __syncthreads();  // FQ ready + ch0 staged (vmcnt(0) drained at barrier)

    // wave-constant bases (u32 indices into FQ)
    const int fqA0 = (2 * wr) * 2080 + 260 * g + 2 * l15;  // qa base (has g)
    const int fqNB = (2 * wr) * 2080 + 2 * l15;            // qb base (no g)

    U2 xp[8][4], xpsw[8][4];
#pragma unroll
    for (int s = 0; s < 8; ++s) {
        int fa = fqA0 + (s >> 2) * 2080 + 32 * (s & 3);
        uint2 qa = *reinterpret_cast<const uint2*>(&FQ[fa]);
        uint2 qb = *reinterpret_cast<const uint2*>(&FQ[fa + 1040]);  // row +8
        xp[s][0].u = qa.x; xp[s][1].u = qa.y; xp[s][2].u = qb.x; xp[s][3].u = qb.y;
#pragma unroll
        for (int i = 0; i < 4; ++i)
            xpsw[s][i].u = (xp[s][i].u >> 16) | (xp[s][i].u << 16);
    }

    f32x4 acc[8][4];
#pragma unroll
    for (int s = 0; s < 8; ++s)
#pragma unroll
        for (int tt = 0; tt < 4; ++tt) acc[s][tt] = f32x4{0.f, 0.f, 0.f, 0.f};

#define PKU(xa, ub) ({ U2 b_; b_.u = (ub); U2 r_; r_.h = (xa).h * b_.h; r_.u; })

#define LOADBF(bf, cc) { _Pragma("unroll") for (int tt = 0; tt < 4; ++tt) \
    bf[tt] = *reinterpret_cast<const f16x8*>( \
        shB + ((cc) & 1) * 8192 + ((wc * 4 + tt) * 64 + lane) * 16); }

#define MFMA4(af, bf) { __builtin_amdgcn_s_setprio(1); \
    _Pragma("unroll") for (int tt = 0; tt < 4; ++tt) \
        acc[s][tt] = __builtin_amdgcn_mfma_f32_16x16x32_f16(af.v, bf[tt], acc[s][tt], 0, 0, 0); \
    __builtin_amdgcn_s_setprio(0); }

    // ---- iter 0 (sg=0, par=0): A from xp regs only
    STAGE(1, 1);
    {
        f16x8 bf[4]; LOADBF(bf, 0);
#pragma unroll
        for (int s = 0; s < 8; ++s) {
            AF af;
#pragma unroll
            for (int i = 0; i < 4; ++i) af.u[i] = PKU(xp[s][i], xp[s][i].u);
            MFMA4(af, bf);
        }
    }
    __syncthreads();
    // ---- iter 1 (sg=0, par=1)
    STAGE(0, 2);
    {
        f16x8 bf[4]; LOADBF(bf, 1);
#pragma unroll
        for (int s = 0; s < 8; ++s) {
            AF af;
#pragma unroll
            for (int i = 0; i < 4; ++i) af.u[i] = PKU(xpsw[s][i], xp[s][i].u);
            MFMA4(af, bf);
        }
    }
    __syncthreads();

#define BODYG(cc)                                                             \
    {                                                                         \
        const int sg_ = (cc) >> 1;                                            \
        const int rb_ = ((2 * g + 8 + sg_) & 15) * 130;                       \
        f16x8 bf[4]; LOADBF(bf, cc);                                          \
        _Pragma("unroll")                                                     \
        for (int s = 0; s < 8; ++s) {                                         \
            int fa = fqA0 + (s >> 2) * 2080 + sg_ * 130 + 32 * (s & 3);       \
            int fb = fqNB + (s >> 2) * 2080 + rb_ + 32 * (s & 3);             \
            uint2 qa = *reinterpret_cast<const uint2*>(&FQ[fa]);              \
            uint2 qb = *reinterpret_cast<const uint2*>(&FQ[fb]);              \
            AF af;                                                            \
            if ((cc) & 1) {                                                   \
                af.u[0] = PKU(xpsw[s][0], qa.x); af.u[1] = PKU(xpsw[s][1], qa.y); \
                af.u[2] = PKU(xpsw[s][2], qb.x); af.u[3] = PKU(xpsw[s][3], qb.y); \
            } else {                                                          \
                af.u[0] = PKU(xp[s][0], qa.x); af.u[1] = PKU(xp[s][1], qa.y); \
                af.u[2] = PKU(xp[s][2], qb.x); af.u[3] = PKU(xp[s][3], qb.y); \
            }                                                                 \
            MFMA4(af, bf);                                                    \
        }                                                                     \
    }

    // iter cc: stage ch(cc+1) into buf((cc+1)&1) (reads done last iter), body cc
#define STEP(cc) { STAGE(((cc) + 1) & 1, (cc) + 1); BODYG(cc); __syncthreads(); }

    STEP(2);  STEP(3);  STEP(4);  STEP(5);  STEP(6);  STEP(7);
    STEP(8);  STEP(9);  STEP(10); STEP(11); STEP(12); STEP(13);
    STEP(14); STEP(15);

    // ---- iter 16 (sg=8, par=0): qa at row 2g+8; linear slots in u[2],u[3]
    STAGE(1, 17);
    {
        f16x8 bf[4]; LOADBF(bf, 16);
#pragma unroll
        for (int s = 0; s < 8; ++s) {
            int fa = fqA0 + (s >> 2) * 2080 + 1040 + 32 * (s & 3);
            uint2 qa = *reinterpret_cast<const uint2*>(&FQ[fa]);
            AF af;
            af.u[0] = PKU(xp[s][0], qa.x); af.u[1] = PKU(xp[s][1], qa.y);
            af.u[2] = xp[s][2].u; af.u[3] = xp[s][3].u;
            MFMA4(af, bf);
        }
    }
    __syncthreads();
    // ---- iter 17 (sg=8, par=1)
    {
        f16x8 bf[4]; LOADBF(bf, 17);
#pragma unroll
        for (int s = 0; s < 8; ++s) {
            int fa = fqA0 + (s >> 2) * 2080 + 1040 + 32 * (s & 3);
            uint2 qa = *reinterpret_cast<const uint2*>(&FQ[fa]);
            AF af;
            af.u[0] = PKU(xpsw[s][0], qa.x); af.u[1] = PKU(xpsw[s][1], qa.y);
            af.u[2] = xp[s][0].u; af.u[3] = xp[s][1].u;
            MFMA4(af, bf);
        }
    }
    __syncthreads();  // all shB reads done; shB becomes eps

#undef STEP
#undef BODYG
#undef MFMA4
#undef LOADBF
#undef PKU
#undef STAGE

    // ---- rv term: wave w handles batch w
    {
        float sum = 0.f;
#pragma unroll
        for (int J = 0; J < 16; ++J) {
            U2 v; v.u = FQ[w * 2080 + J * 130 + 2 * lane];
            sum += rs[2 * J] * (float)v.h[0] + rs[2 * J + 1] * (float)v.h[1];
        }
#pragma unroll
        for (int off = 32; off; off >>= 1) sum += __shfl_xor(sum, off);
        if (lane == 0) rvb[w] = sum;
    }

    // ---- epilogue: s(b,d) = sum_h A1*(w1+A2) + b1*A2   (+ b1*w1 in cnst)
    float* eps = reinterpret_cast<float*>(shB);  // [2][16*64]
    float bs0 = 0.f, bs1 = 0.f;
#pragma unroll
    for (int s = 0; s < 8; ++s) {
        if (wc == 1) {
#pragma unroll
            for (int tt = 0; tt < 4; ++tt) {
                float w1v = w1s[16 * tt + l15];
                float b1v = b1s[16 * tt + l15];
#pragma unroll
                for (int r = 0; r < 4; ++r) {
                    float a = acc[s][tt][r];
                    eps[wr * 1024 + EPOS(4 * g + r, 16 * tt + l15)] = a + w1v;
                    float term = b1v * a;
                    if (s < 4) bs0 += term; else bs1 += term;
                }
            }
        }
        __syncthreads();
        if (wc == 0) {
#pragma unroll
            for (int tt = 0; tt < 4; ++tt)
#pragma unroll
                for (int r = 0; r < 4; ++r) {
                    float term = acc[s][tt][r] *
                                 eps[wr * 1024 + EPOS(4 * g + r, 16 * tt + l15)];
                    if (s < 4) bs0 += term; else bs1 += term;
                }
        }
        __syncthreads();
    }
#pragma unroll
    for (int off = 32; off; off >>= 1) {
        bs0 += __shfl_xor(bs0, off);
        bs1 += __shfl_xor(bs1, off);
    }
    if (lane == 0) { obuf[w][0] = bs0; obuf[w][1] = bs1; }
    __syncthreads();
    if (t < 4) {
        int bt = t;
        out[blk * 4 + bt] = cnst[0] + rvb[bt] +
                            obuf[2 * (bt >> 1) + 0][bt & 1] +
                            obuf[2 * (bt >> 1) + 1][bt & 1];
    }
}

extern "C" void kernel_launch(void* const* d_in, const int* in_sizes, int n_in,
                              void* d_out, int out_size, void* d_ws, size_t ws_size,
                              hipStream_t stream) {
    const float* x0    = (const float*)d_in[0];
    const float* W1    = (const float*)d_in[1];
    const float* b1    = (const float*)d_in[2];
    const float* W2    = (const float*)d_in[3];
    const float* b2    = (const float*)d_in[4];
    const float* W3    = (const float*)d_in[5];
    const float* b3    = (const float*)d_in[6];
    const float* W_out = (const float*)d_in[7];
    const float* b_out = (const float*)d_in[8];

    char* wsb = (char*)d_ws;
    f16*   Wfrag = (f16*)wsb;                       // 18*4096 halves = 147456 B
    float* W3effp = (float*)(wsb + 147456);         // 2048 floats
    float* rvecp = W3effp + 2048;                   // 32
    float* cnstp = rvecp + 32;                      // 1
    float* outp  = (float*)d_out;

    hipLaunchKernelGGL(pre_w3eff, dim3(8),   dim3(256), 0, stream, W3, W_out, W3effp);
    hipLaunchKernelGGL(pre_rest,  dim3(129), dim3(256), 0, stream,
                       W1, b1, W2, b2, b3, W_out, b_out, W3effp, Wfrag, rvecp, cnstp);
    hipLaunchKernelGGL(cin_main,  dim3(512), dim3(256), 0, stream,
                       x0, Wfrag, b1, W_out, rvecp, cnstp, outp);
}

// Round 10
// 41.181 us; speedup vs baseline: 1.0026x; 1.0026x over previous
//
#include <hip/hip_runtime.h>

typedef _Float16 f16;
typedef _Float16 f16x2 __attribute__((ext_vector_type(2)));
typedef __fp16 fp16x2 __attribute__((ext_vector_type(2)));
typedef _Float16 f16x8 __attribute__((ext_vector_type(8)));
typedef float f32x4 __attribute__((ext_vector_type(4)));
typedef unsigned int u32;

union U2 { u32 u; f16x2 h; fp16x2 h2; };
union AF { f16x8 v; u32 u[4]; };

// ---------------- pre kernel 1: W3eff (computed ONCE, coalesced, MLP'd) ----
__global__ __launch_bounds__(256) void pre_w3eff(
    const float* __restrict__ W3, const float* __restrict__ W_out,
    float* __restrict__ W3eff) {
    const int idx = blockIdx.x * 256 + threadIdx.x;  // 2048 = (h,m)
    float acc[8] = {0.f, 0.f, 0.f, 0.f, 0.f, 0.f, 0.f, 0.f};
#pragma unroll
    for (int ob = 0; ob < 8; ++ob)
#pragma unroll
        for (int oi = 0; oi < 8; ++oi) {
            int o = ob * 8 + oi;
            acc[oi] += W_out[128 + o] * W3[o * 2048 + idx];
        }
    float s = 0.f;
#pragma unroll
    for (int oi = 0; oi < 8; ++oi) s += acc[oi];
    W3eff[idx] = s;
}

// ---------------- pre kernel 2: Wfrag + rvec + cnst (unchanged format) -----
__global__ __launch_bounds__(256) void pre_rest(
    const float* __restrict__ W1, const float* __restrict__ b1,
    const float* __restrict__ W2, const float* __restrict__ b2,
    const float* __restrict__ b3, const float* __restrict__ W_out,
    const float* __restrict__ b_out, const float* __restrict__ W3eff_g,
    f16* __restrict__ Wfrag, float* __restrict__ rvec, float* __restrict__ cnst) {
    const int blk = blockIdx.x, t = threadIdx.x;
    if (blk < 64) {
        const int h = blk;
        __shared__ float w3e[2048];
        __shared__ float w2s[2048];
        __shared__ float wo2[64];
#pragma unroll
        for (int i = 0; i < 8; ++i) {
            int idx = t + 256 * i;
            w3e[idx] = W3eff_g[idx];
            w2s[idx] = W2[((idx >> 5) * 64 + h) * 32 + (idx & 31)];
        }
        if (t < 64) wo2[t] = W_out[64 + t];
        __syncthreads();
        for (int idx = t; idx < 576; idx += 256) {
            int c = idx >> 5, kk = idx & 31;
            int sg = c >> 1, par = c & 1, A = kk >> 1, z = kk & 1;
            int B = (A + sg) & 15;
            float val = 0.f;
            if (sg == 0 && par == 1 && z == 1) {
                val = 0.f;
            } else if (sg == 8 && A >= 8) {
                int m = par ? (kk - 16) : kk;
                float s = 0.f;
#pragma unroll 8
                for (int o = 0; o < 64; ++o) s += wo2[o] * w2s[o * 32 + m];
                val = s;
            } else {
                int a = 2 * A + (par ? (1 - z) : z);
                int bq = 2 * B + z;
                float s = 0.f;
                if (a == bq) {
#pragma unroll 8
                    for (int o = 0; o < 64; ++o)
                        s += w3e[o * 32 + a] * w2s[o * 32 + a];
                } else {
#pragma unroll 8
                    for (int o = 0; o < 64; ++o)
                        s += w3e[o * 32 + bq] * w2s[o * 32 + a] +
                             w3e[o * 32 + a] * w2s[o * 32 + bq];
                }
                val = s;
            }
            int g = (kk >> 2) & 3, bb = (kk & 3) + 4 * (kk >> 4);
            int t4 = 4 + (h >> 4), l = 16 * g + (h & 15);
            Wfrag[((c * 8 + t4) * 64 + l) * 8 + bb] = (f16)val;
        }
    } else if (blk < 128) {
        const int h = blk - 64;
        __shared__ float w1r[1024];
        for (int i = t; i < 1024; i += 256) w1r[i] = W1[h * 1024 + i];
        __syncthreads();
        for (int idx = t; idx < 576; idx += 256) {
            int c = idx >> 5, kk = idx & 31;
            int sg = c >> 1, par = c & 1, A = kk >> 1, z = kk & 1;
            int B = (A + sg) & 15;
            float val = 0.f;
            if ((sg == 0 && par == 1 && z == 1) || (sg == 8 && A >= 8)) {
                val = 0.f;
            } else {
                int a = 2 * A + (par ? (1 - z) : z);
                int bq = 2 * B + z;
                val = (a == bq) ? w1r[33 * a] : (w1r[32 * a + bq] + w1r[32 * bq + a]);
            }
            int g = (kk >> 2) & 3, bb = (kk & 3) + 4 * (kk >> 4);
            int t4 = h >> 4, l = 16 * g + (h & 15);
            Wfrag[((c * 8 + t4) * 64 + l) * 8 + bb] = (f16)val;
        }
    } else {
        if (t < 32) {
            float acc[8] = {0.f, 0.f, 0.f, 0.f, 0.f, 0.f, 0.f, 0.f};
#pragma unroll
            for (int hb = 0; hb < 8; ++hb)
#pragma unroll
                for (int hi = 0; hi < 8; ++hi) {
                    int h = hb * 8 + hi;
                    acc[hi] += b2[h] * W3eff_g[h * 32 + t];
                }
            float r = 0.f;
#pragma unroll
            for (int hi = 0; hi < 8; ++hi) r += acc[hi];
            rvec[t] = r;
        }
        if (t >= 64 && t < 128) {
            int o = t - 64;
            float v = b1[o] * W_out[o] + b2[o] * W_out[64 + o] +
                      b3[o] * W_out[128 + o];
#pragma unroll
            for (int off = 32; off; off >>= 1) v += __shfl_xor(v, off);
            if (o == 0) cnst[0] = b_out[0] + 64.f * v;
        }
    }
}

// ---------------- main kernel ----------------

__device__ __forceinline__ void gld16(const void* g, void* l) {
    __builtin_amdgcn_global_load_lds(
        (const __attribute__((address_space(1))) u32*)g,
        (__attribute__((address_space(3))) u32*)l, 16, 0, 0);
}

#define EPOS(row, col) ((row) * 64 + (((col) + 4 * (row)) & 63))

// Block: 4 batches x 128 cols, 4 waves. Same structure as r9 (verified) but
// xpsw deleted: halfword swap recomputed inline (v_alignbit, bit-identical)
// to cut ~32 VGPRs -> fit 2 waves/SIMD on the unified VGPR/AGPR file.
__global__ __launch_bounds__(256, 2) void cin_main(
    const float* __restrict__ x0, const f16* __restrict__ Wfrag,
    const float* __restrict__ b1, const float* __restrict__ W_out,
    const float* __restrict__ rvec, const float* __restrict__ cnst,
    float* __restrict__ out) {
    __shared__ __align__(16) u32 FQ[4 * 2080];   // 33280 B
    __shared__ __align__(16) char shB[16384];    // B dbuf; epilogue eps aliases
    __shared__ float b1s[64], w1s[64], rs[32], rvb[4], obuf[4][2];

    const int t = threadIdx.x;
    const int w = t >> 6, lane = t & 63;
    const int wr = w >> 1, wc = w & 1;
    const int g = (lane >> 4) & 3, l15 = lane & 15;
    const int blk = blockIdx.x;

    const char* WfB = reinterpret_cast<const char*>(Wfrag);

#define STAGE(buf, ch)                                              \
    do {                                                            \
        const char* gs_ = WfB + (ch) * 8192 + w * 2048 + lane * 16; \
        char* ls_ = shB + (buf) * 8192 + w * 2048;                  \
        gld16(gs_, ls_);                                            \
        gld16(gs_ + 1024, ls_ + 1024);                              \
    } while (0)

    STAGE(0, 0);

    {   // stage x0 (4 batches) -> FQ (16 rows per batch)
        const float* src = x0 + (size_t)blk * 8192;
        const int J = t >> 4, l = t & 15;  // J in [0,16)
        int r0 = 2 * J, r1 = 2 * J + 1, r2_ = (2 * J + 2) & 31, r3_ = (2 * J + 3) & 31;
#pragma unroll
        for (int bl = 0; bl < 4; ++bl) {
            const float* sb = src + bl * 2048;
#pragma unroll
            for (int k2 = 0; k2 < 4; ++k2) {
                int d = 16 * k2 + l;
                U2 u0, u1;
                u0.h2 = __builtin_amdgcn_cvt_pkrtz(sb[r0 * 64 + d], sb[r1 * 64 + d]);
                u1.h2 = __builtin_amdgcn_cvt_pkrtz(sb[r2_ * 64 + d], sb[r3_ * 64 + d]);
                uint2 ent; ent.x = u0.u; ent.y = u1.u;
                *reinterpret_cast<uint2*>(&FQ[bl * 2080 + J * 130 + 2 * d]) = ent;
            }
        }
    }
    if (t < 64) { b1s[t] = b1[t]; w1s[t] = W_out[t]; }
    if (t >= 64 && t < 96) rs[t - 64] = rvec[t - 64];
    __syncthreads();  // FQ ready + ch0 staged (vmcnt(0) drained at barrier)

    // wave-constant bases (u32 indices into FQ)
    const int fqA0 = (2 * wr) * 2080 + 260 * g + 2 * l15;  // qa base (has g)
    const int fqNB = (2 * wr) * 2080 + 2 * l15;            // qb base (no g)

    U2 xp[8][4];
#pragma unroll
    for (int s = 0; s < 8; ++s) {
        int fa = fqA0 + (s >> 2) * 2080 + 32 * (s & 3);
        uint2 qa = *reinterpret_cast<const uint2*>(&FQ[fa]);
        uint2 qb = *reinterpret_cast<const uint2*>(&FQ[fa + 1040]);  // row +8
        xp[s][0].u = qa.x; xp[s][1].u = qa.y; xp[s][2].u = qb.x; xp[s][3].u = qb.y;
    }

    f32x4 acc[8][4];
#pragma unroll
    for (int s = 0; s < 8; ++s)
#pragma unroll
        for (int tt = 0; tt < 4; ++tt) acc[s][tt] = f32x4{0.f, 0.f, 0.f, 0.f};

#define SWP(uu) (((uu) >> 16) | ((uu) << 16))
#define PKU(ua, ub) ({ U2 a_; a_.u = (ua); U2 b_; b_.u = (ub); \
                       U2 r_; r_.h = a_.h * b_.h; r_.u; })

#define LOADBF(bf, cc) { _Pragma("unroll") for (int tt = 0; tt < 4; ++tt) \
    bf[tt] = *reinterpret_cast<const f16x8*>( \
        shB + ((cc) & 1) * 8192 + ((wc * 4 + tt) * 64 + lane) * 16); }

#define MFMA4(af, bf) { __builtin_amdgcn_s_setprio(1); \
    _Pragma("unroll") for (int tt = 0; tt < 4; ++tt) \
        acc[s][tt] = __builtin_amdgcn_mfma_f32_16x16x32_f16(af.v, bf[tt], acc[s][tt], 0, 0, 0); \
    __builtin_amdgcn_s_setprio(0); }

    // ---- iter 0 (sg=0, par=0): A from xp regs only
    STAGE(1, 1);
    {
        f16x8 bf[4]; LOADBF(bf, 0);
#pragma unroll
        for (int s = 0; s < 8; ++s) {
            AF af;
#pragma unroll
            for (int i = 0; i < 4; ++i) af.u[i] = PKU(xp[s][i].u, xp[s][i].u);
            MFMA4(af, bf);
        }
    }
    __syncthreads();
    // ---- iter 1 (sg=0, par=1)
    STAGE(0, 2);
    {
        f16x8 bf[4]; LOADBF(bf, 1);
#pragma unroll
        for (int s = 0; s < 8; ++s) {
            AF af;
#pragma unroll
            for (int i = 0; i < 4; ++i) af.u[i] = PKU(SWP(xp[s][i].u), xp[s][i].u);
            MFMA4(af, bf);
        }
    }
    __syncthreads();

#define BODYG(cc)                                                             \
    {                                                                         \
        const int sg_ = (cc) >> 1;                                            \
        const int rb_ = ((2 * g + 8 + sg_) & 15) * 130;                       \
        f16x8 bf[4]; LOADBF(bf, cc);                                          \
        _Pragma("unroll")                                                     \
        for (int s = 0; s < 8; ++s) {                                         \
            int fa = fqA0 + (s >> 2) * 2080 + sg_ * 130 + 32 * (s & 3);       \
            int fb = fqNB + (s >> 2) * 2080 + rb_ + 32 * (s & 3);             \
            uint2 qa = *reinterpret_cast<const uint2*>(&FQ[fa]);              \
            uint2 qb = *reinterpret_cast<const uint2*>(&FQ[fb]);              \
            AF af;                                                            \
            if ((cc) & 1) {                                                   \
                af.u[0] = PKU(SWP(xp[s][0].u), qa.x);                         \
                af.u[1] = PKU(SWP(xp[s][1].u), qa.y);                         \
                af.u[2] = PKU(SWP(xp[s][2].u), qb.x);                         \
                af.u[3] = PKU(SWP(xp[s][3].u), qb.y);                         \
            } else {                                                          \
                af.u[0] = PKU(xp[s][0].u, qa.x);                              \
                af.u[1] = PKU(xp[s][1].u, qa.y);                              \
                af.u[2] = PKU(xp[s][2].u, qb.x);                              \
                af.u[3] = PKU(xp[s][3].u, qb.y);                              \
            }                                                                 \
            MFMA4(af, bf);                                                    \
        }                                                                     \
    }

    // iter cc: stage ch(cc+1) into buf((cc+1)&1) (reads done last iter), body cc
#define STEP(cc) { STAGE(((cc) + 1) & 1, (cc) + 1); BODYG(cc); __syncthreads(); }

    STEP(2);  STEP(3);  STEP(4);  STEP(5);  STEP(6);  STEP(7);
    STEP(8);  STEP(9);  STEP(10); STEP(11); STEP(12); STEP(13);
    STEP(14); STEP(15);

    // ---- iter 16 (sg=8, par=0): qa at row 2g+8; linear slots in u[2],u[3]
    STAGE(1, 17);
    {
        f16x8 bf[4]; LOADBF(bf, 16);
#pragma unroll
        for (int s = 0; s < 8; ++s) {
            int fa = fqA0 + (s >> 2) * 2080 + 1040 + 32 * (s & 3);
            uint2 qa = *reinterpret_cast<const uint2*>(&FQ[fa]);
            AF af;
            af.u[0] = PKU(xp[s][0].u, qa.x); af.u[1] = PKU(xp[s][1].u, qa.y);
            af.u[2] = xp[s][2].u; af.u[3] = xp[s][3].u;
            MFMA4(af, bf);
        }
    }
    __syncthreads();
    // ---- iter 17 (sg=8, par=1)
    {
        f16x8 bf[4]; LOADBF(bf, 17);
#pragma unroll
        for (int s = 0; s < 8; ++s) {
            int fa = fqA0 + (s >> 2) * 2080 + 1040 + 32 * (s & 3);
            uint2 qa = *reinterpret_cast<const uint2*>(&FQ[fa]);
            AF af;
            af.u[0] = PKU(SWP(xp[s][0].u), qa.x);
            af.u[1] = PKU(SWP(xp[s][1].u), qa.y);
            af.u[2] = xp[s][0].u; af.u[3] = xp[s][1].u;
            MFMA4(af, bf);
        }
    }
    __syncthreads();  // all shB reads done; shB becomes eps

#undef STEP
#undef BODYG
#undef MFMA4
#undef LOADBF
#undef PKU
#undef SWP
#undef STAGE

    // ---- rv term: wave w handles batch w
    {
        float sum = 0.f;
#pragma unroll
        for (int J = 0; J < 16; ++J) {
            U2 v; v.u = FQ[w * 2080 + J * 130 + 2 * lane];
            sum += rs[2 * J] * (float)v.h[0] + rs[2 * J + 1] * (float)v.h[1];
        }
#pragma unroll
        for (int off = 32; off; off >>= 1) sum += __shfl_xor(sum, off);
        if (lane == 0) rvb[w] = sum;
    }

    // ---- epilogue: s(b,d) = sum_h A1*(w1+A2) + b1*A2   (+ b1*w1 in cnst)
    float* eps = reinterpret_cast<float*>(shB);  // [2][16*64]
    float bs0 = 0.f, bs1 = 0.f;
#pragma unroll
    for (int s = 0; s < 8; ++s) {
        if (wc == 1) {
#pragma unroll
            for (int tt = 0; tt < 4; ++tt) {
                float w1v = w1s[16 * tt + l15];
                float b1v = b1s[16 * tt + l15];
#pragma unroll
                for (int r = 0; r < 4; ++r) {
                    float a = acc[s][tt][r];
                    eps[wr * 1024 + EPOS(4 * g + r, 16 * tt + l15)] = a + w1v;
                    float term = b1v * a;
                    if (s < 4) bs0 += term; else bs1 += term;
                }
            }
        }
        __syncthreads();
        if (wc == 0) {
#pragma unroll
            for (int tt = 0; tt < 4; ++tt)
#pragma unroll
                for (int r = 0; r < 4; ++r) {
                    float term = acc[s][tt][r] *
                                 eps[wr * 1024 + EPOS(4 * g + r, 16 * tt + l15)];
                    if (s < 4) bs0 += term; else bs1 += term;
                }
        }
        __syncthreads();
    }
#pragma unroll
    for (int off = 32; off; off >>= 1) {
        bs0 += __shfl_xor(bs0, off);
        bs1 += __shfl_xor(bs1, off);
    }
    if (lane == 0) { obuf[w][0] = bs0; obuf[w][1] = bs1; }
    __syncthreads();
    if (t < 4) {
        int bt = t;
        out[blk * 4 + bt] = cnst[0] + rvb[bt] +
                            obuf[2 * (bt >> 1) + 0][bt & 1] +
                            obuf[2 * (bt >> 1) + 1][bt & 1];
    }
}

extern "C" void kernel_launch(void* const* d_in, const int* in_sizes, int n_in,
                              void* d_out, int out_size, void* d_ws, size_t ws_size,
                              hipStream_t stream) {
    const float* x0    = (const float*)d_in[0];
    const float* W1    = (const float*)d_in[1];
    const float* b1    = (const float*)d_in[2];
    const float* W2    = (const float*)d_in[3];
    const float* b2    = (const float*)d_in[4];
    const float* W3    = (const float*)d_in[5];
    const float* b3    = (const float*)d_in[6];
    const float* W_out = (const float*)d_in[7];
    const float* b_out = (const float*)d_in[8];

    char* wsb = (char*)d_ws;
    f16*   Wfrag = (f16*)wsb;                       // 18*4096 halves = 147456 B
    float* W3effp = (float*)(wsb + 147456);         // 2048 floats
    float* rvecp = W3effp + 2048;                   // 32
    float* cnstp = rvecp + 32;                      // 1
    float* outp  = (float*)d_out;

    hipLaunchKernelGGL(pre_w3eff, dim3(8),   dim3(256), 0, stream, W3, W_out, W3effp);
    hipLaunchKernelGGL(pre_rest,  dim3(129), dim3(256), 0, stream,
                       W1, b1, W2, b2, b3, W_out, b_out, W3effp, Wfrag, rvecp, cnstp);
    hipLaunchKernelGGL(cin_main,  dim3(512), dim3(256), 0, stream,
                       x0, Wfrag, b1, W_out, rvecp, cnstp, outp);
}